// Round 6
// baseline (115.308 us; speedup 1.0000x reference)
//
#include <hip/hip_runtime.h>
#include <cstdint>

#define B_SZ 8192
#define D_SZ 512
#define K_SZ 2048
#define G_SZ 4096
#define EPSV 1e-8f
// 1/TEMP
#define INV_T 2.0f

typedef float floatx16 __attribute__((ext_vector_type(16)));
typedef int intx8 __attribute__((ext_vector_type(8)));

// pack 8 fp32 -> 8 fp8 e4m3 (OCP, RNE, saturating) as int2
__device__ __forceinline__ int2 pack_fp8x8(float4 a0, float4 a1) {
    int w0 = __builtin_amdgcn_cvt_pk_fp8_f32(a0.x, a0.y, 0, false);
    w0 = __builtin_amdgcn_cvt_pk_fp8_f32(a0.z, a0.w, w0, true);
    int w1 = __builtin_amdgcn_cvt_pk_fp8_f32(a1.x, a1.y, 0, false);
    w1 = __builtin_amdgcn_cvt_pk_fp8_f32(a1.z, a1.w, w1, true);
    return make_int2(w0, w1);
}

// ---------------------------------------------------------------------------
// Kernel 1: merged prep+gather (unchanged from R4/R5, verified). A and G
// stored K-BLOCK-MAJOR: A_t[kb][row][64], G_t[kb][g][64] (kb 0..7).
// ---------------------------------------------------------------------------
__global__ __launch_bounds__(256) void k_prep(
    const float* __restrict__ zi, const float* __restrict__ zj,
    const int* __restrict__ perm,
    float* __restrict__ ri_arr, float* __restrict__ pos_arr,
    unsigned char* __restrict__ A,
    float4* __restrict__ kmeta, unsigned char* __restrict__ G,
    float* __restrict__ rowacc, float* __restrict__ out)
{
    int w = threadIdx.x >> 6, l = threadIdx.x & 63;
    if (blockIdx.x < 2048) {
        if (blockIdx.x < 64)
            rowacc[blockIdx.x * 256 + threadIdx.x] = 0.f;   // pe[8192] ++ pc[8192]
        if (blockIdx.x == 0 && threadIdx.x < 3) out[threadIdx.x] = 0.f;
        int row = blockIdx.x * 4 + w;
        const float4* zi4 = (const float4*)(zi + (size_t)row * D_SZ);
        const float4* zj4 = (const float4*)(zj + (size_t)row * D_SZ);
        float4 a0 = zi4[2 * l], a1 = zi4[2 * l + 1];
        float4 b0 = zj4[2 * l], b1 = zj4[2 * l + 1];
        float si = a0.x * a0.x + a0.y * a0.y + a0.z * a0.z + a0.w * a0.w
                 + a1.x * a1.x + a1.y * a1.y + a1.z * a1.z + a1.w * a1.w;
        float sj = b0.x * b0.x + b0.y * b0.y + b0.z * b0.z + b0.w * b0.w
                 + b1.x * b1.x + b1.y * b1.y + b1.z * b1.z + b1.w * b1.w;
        float dd = a0.x * b0.x + a0.y * b0.y + a0.z * b0.z + a0.w * b0.w
                 + a1.x * b1.x + a1.y * b1.y + a1.z * b1.z + a1.w * b1.w;
        for (int m = 1; m < 64; m <<= 1) {
            si += __shfl_xor(si, m);
            sj += __shfl_xor(sj, m);
            dd += __shfl_xor(dd, m);
        }
        if (l == 0) {
            float ni = sqrtf(si), nj = sqrtf(sj);
            ri_arr[row] = INV_T / fmaxf(ni, 1e-6f);   // norms ~22; eps never binds
            pos_arr[row] = dd / fmaxf(ni * nj, EPSV) * INV_T;
        }
        // kb-major store: A_t[l>>3][row][ (l&7)*8 .. +8 )
        *(int2*)(A + ((size_t)(l >> 3) * B_SZ + row) * 64 + (l & 7) * 8)
            = pack_fp8x8(a0, a1);
    } else {
        __shared__ float srj[4];
        int g = (blockIdx.x - 2048) * 4 + w;        // 0..4095
        int c0 = perm[g >> 1];
        int c = c0 + (g & 1);                       // actual z_j row
        const float4* src = (const float4*)(zj + (size_t)c * D_SZ);
        float4 a0 = src[2 * l], a1 = src[2 * l + 1];
        float s = a0.x * a0.x + a0.y * a0.y + a0.z * a0.z + a0.w * a0.w
                + a1.x * a1.x + a1.y * a1.y + a1.z * a1.z + a1.w * a1.w;
        for (int m = 1; m < 64; m <<= 1) s += __shfl_xor(s, m);
        if (l == 0) srj[w] = 1.0f / fmaxf(sqrtf(s), 1e-6f);
        __syncthreads();
        if ((w & 1) == 0 && l == 0)
            kmeta[g >> 1] = make_float4(srj[w], srj[w + 1],
                                        __int_as_float(c0), 0.f);
        *(int2*)(G + ((size_t)(l >> 3) * G_SZ + g) * 64 + (l & 7) * 8)
            = pack_fp8x8(a0, a1);
    }
}

// ---------------------------------------------------------------------------
// Kernel 2 (R16): BARRIER-FREE REG-STREAMING GEMM.
// 512 blocks x 256 thr (4 waves). Block = 128 anchors x one 512-g range;
// wave = 32 anchors x 512 g. A-panel (32 rows x 512B = 64 VGPR) persistent
// in registers; G streamed in 32-g chunks (full K, 64 VGPR) through a
// 2-chunk register double buffer. Per chunk: 8 MFMAs (K-accumulate) ->
// immediate pair-select epilogue into running pe/pc. NO operand LDS, NO
// per-step barriers, NO inline asm: nothing is barrier-coupled to the
// slowest load; latency hidden by 16-deep per-wave MLP + 2 waves/SIMD.
// Operand bytes per lane identical to the verified LDS version (lane l:
// row (l&31), k-bytes [q*32, q*32+32) of each 64B kb-slab) -> identical
// MFMA semantics. kb-major layout => every load is part of a dense 2KB
// burst (32 contiguous rows x 64B per kb-slab).
// XCD map: range = bid&7 (G slab 256KB, L2-resident per XCD).
// ---------------------------------------------------------------------------
__global__ __launch_bounds__(256, 2) void k_gemm(
    const unsigned char* __restrict__ A,    // [8][8192][64] fp8  kb-major
    const unsigned char* __restrict__ G,    // [8][4096][64] fp8  kb-major
    const float4* __restrict__ kmeta,       // [2048]  {rj0, rj1, c0f, -}
    const float* __restrict__ ri_arr,       // [8192]  INV_T/ni
    const float* __restrict__ pos_arr,      // [8192]
    float* __restrict__ rowacc)             // [2][8192] atomic accumulators
{
    __shared__ float4 kms[256];             // this range's 256 column pairs
    const int tid = threadIdx.x;
    const int l = tid & 63, w = tid >> 6;   // wave 0..3
    const int ln = l & 31, q = l >> 5;      // 32x32 MFMA lane decomposition

    const int bid = blockIdx.x;
    const int xcd = bid & 7;                // g-range 0..7 (XCD-local slab)
    const int slot = bid >> 3;              // 0..63 anchor panel (128 rows)
    const int gBase = xcd * 512;
    const int aBase = slot * 128 + w * 32;  // this wave's 32 anchors

    // kms: one float4 per thread, one barrier total
    kms[tid] = kmeta[xcd * 256 + tid];
    __syncthreads();

    const int anc = aBase + ln;             // this lane's anchor column
    const float riv = ri_arr[anc];          // INV_T / ni
    const float pv = pos_arr[anc];

    // ---- A panel -> registers (persistent, 16 int4 = 64 VGPR) ----
    // lane l: row aBase + (l&31), bytes [q*32, q*32+32) of each kb-slab
    int4 apan[16];
    #pragma unroll
    for (int kb = 0; kb < 8; ++kb) {
        const unsigned char* s =
            A + ((size_t)kb * B_SZ + aBase + ln) * 64 + q * 32;
        apan[2 * kb]     = *(const int4*)(s);
        apan[2 * kb + 1] = *(const int4*)(s + 16);
    }

    float pe = 0.f, pc = 0.f;

    // G chunk loader: 32 g-rows x full K -> 16 int4 (dense 2KB per kb-slab)
    auto LOADG = [&](int4* gb, int c) {
        const unsigned char* gs =
            G + (size_t)(gBase + c * 32 + ln) * 64 + q * 32;
        #pragma unroll
        for (int kb = 0; kb < 8; ++kb) {
            const unsigned char* s = gs + (size_t)kb * (G_SZ * 64);
            gb[2 * kb]     = *(const int4*)(s);
            gb[2 * kb + 1] = *(const int4*)(s + 16);
        }
    };

    // per-chunk compute: 8 K-accumulating MFMAs + immediate epilogue
    auto COMPUTE = [&](const int4* gb, int c) {
        floatx16 acc = {};
        #pragma unroll
        for (int kb = 0; kb < 8; ++kb) {
            intx8 gf, af;
            int4 glo = gb[2 * kb], ghi = gb[2 * kb + 1];
            gf[0] = glo.x; gf[1] = glo.y; gf[2] = glo.z; gf[3] = glo.w;
            gf[4] = ghi.x; gf[5] = ghi.y; gf[6] = ghi.z; gf[7] = ghi.w;
            int4 alo = apan[2 * kb], ahi = apan[2 * kb + 1];
            af[0] = alo.x; af[1] = alo.y; af[2] = alo.z; af[3] = alo.w;
            af[4] = ahi.x; af[5] = ahi.y; af[6] = ahi.z; af[7] = ahi.w;
            acc = __builtin_amdgcn_mfma_scale_f32_32x32x64_f8f6f4(
                gf, af, acc,
                0, 0,                       // cbsz/blgp = fp8 e4m3
                0, 0x7f7f7f7f,              // scale A: all-ones (2^0)
                0, 0x7f7f7f7f);             // scale B: all-ones (2^0)
        }
        // C/D layout (32x32): col = anchor = ln, local g = (re&3) +
        // 8*(re>>2) + 4*q. Regs 4j..4j+3 = 4 consecutive g, i.e. range-local
        // column pairs kidx = c*16 + 4j + 2q and kidx+1.
        #pragma unroll
        for (int j = 0; j < 4; ++j) {
            int kidx = c * 16 + 4 * j + 2 * q;
            float4 m0 = kms[kidx];
            float4 m1 = kms[kidx + 1];
            #pragma unroll
            for (int p = 0; p < 2; ++p) {
                float4 md = p ? m1 : m0;
                int c0 = __float_as_int(md.z);
                int re = 4 * j + 2 * p;     // even-g reg; odd is re+1
                bool sel = (c0 >= anc);                 // use column c0+1
                float v = sel ? acc[re + 1] : acc[re];
                float rj = sel ? md.y : md.x;
                float logit = v * riv * rj;
                pe += __expf(logit);
                pc += (logit > pv) ? 1.f : 0.f;
            }
        }
    };

    // ---- main loop: 16 chunks, register double-buffer, fully static ----
    int4 gb0[16], gb1[16];
    LOADG(gb0, 0);
    #pragma unroll
    for (int c = 0; c < 16; ++c) {
        if ((c & 1) == 0) {
            if (c < 15) LOADG(gb1, c + 1);  // next chunk in flight
            COMPUTE(gb0, c);
        } else {
            if (c < 15) LOADG(gb0, c + 1);
            COMPUTE(gb1, c);
        }
    }

    // ---- reduce q-halves and accumulate ----
    pe += __shfl_xor(pe, 32);
    pc += __shfl_xor(pc, 32);
    if (q == 0) {
        atomicAdd(&rowacc[anc], pe);
        atomicAdd(&rowacc[B_SZ + anc], pc);
    }
}

// ---------------------------------------------------------------------------
// Kernel 3: tiny finalize — one thread per row, then block+global reduce.
// ---------------------------------------------------------------------------
__global__ __launch_bounds__(256) void k_final(
    const float* __restrict__ rowacc, const float* __restrict__ pos_arr,
    float* __restrict__ out)
{
    int row = blockIdx.x * 256 + threadIdx.x;
    float pe = rowacc[row];
    float pc = rowacc[B_SZ + row];
    float pos = pos_arr[row];
    float loss = logf(__expf(pos) + pe) - pos;   // logsumexp - pos (logits bounded)
    float a1 = (pc < 0.5f) ? 1.f : 0.f;          // no neg strictly > pos
    float a5 = (pc < 4.5f) ? 1.f : 0.f;          // at most 4 negs strictly > pos
    for (int m = 1; m < 64; m <<= 1) {
        loss += __shfl_xor(loss, m);
        a1 += __shfl_xor(a1, m);
        a5 += __shfl_xor(a5, m);
    }
    __shared__ float red[3][4];
    int w = threadIdx.x >> 6, l = threadIdx.x & 63;
    if (l == 0) { red[0][w] = loss; red[1][w] = a1; red[2][w] = a5; }
    __syncthreads();
    if (threadIdx.x == 0) {
        float L = red[0][0] + red[0][1] + red[0][2] + red[0][3];
        float A1 = red[1][0] + red[1][1] + red[1][2] + red[1][3];
        float A5 = red[2][0] + red[2][1] + red[2][2] + red[2][3];
        atomicAdd(&out[0], L / (float)B_SZ);
        atomicAdd(&out[1], A1 * (100.f / (float)B_SZ));
        atomicAdd(&out[2], A5 * (100.f / (float)B_SZ));
    }
}

// ---------------------------------------------------------------------------
extern "C" void kernel_launch(void* const* d_in, const int* in_sizes, int n_in,
                              void* d_out, int out_size, void* d_ws, size_t ws_size,
                              hipStream_t stream)
{
    const float* zi = (const float*)d_in[0];
    const float* zj = (const float*)d_in[1];
    const int* perm = (const int*)d_in[2];
    float* out = (float*)d_out;

    // workspace layout (all 16B aligned)
    char* p = (char*)d_ws;
    unsigned char* A = (unsigned char*)p;    p += (size_t)B_SZ * D_SZ;          // 4 MB, kb-major
    unsigned char* G = (unsigned char*)p;    p += (size_t)2 * K_SZ * D_SZ;      // 2 MB, kb-major
    float* ri_arr = (float*)p;               p += (size_t)B_SZ * 4;
    float* pos_arr = (float*)p;              p += (size_t)B_SZ * 4;
    float4* kmeta = (float4*)p;              p += (size_t)K_SZ * 16;            // 32 KB
    float* rowacc = (float*)p;               p += (size_t)2 * B_SZ * 4;         // 64 KB

    k_prep<<<2048 + 1024, 256, 0, stream>>>(zi, zj, perm, ri_arr, pos_arr, A,
                                            kmeta, G, rowacc, out);
    k_gemm<<<512, 256, 0, stream>>>(A, G, kmeta, ri_arr, pos_arr, rowacc);
    k_final<<<32, 256, 0, stream>>>(rowacc, pos_arr, out);
}

// Round 8
// 108.663 us; speedup vs baseline: 1.0611x; 1.0611x over previous
//
#include <hip/hip_runtime.h>
#include <cstdint>

#define B_SZ 8192
#define D_SZ 512
#define K_SZ 2048
#define G_SZ 4096
#define EPSV 1e-8f
// 1/TEMP
#define INV_T 2.0f

typedef float floatx16 __attribute__((ext_vector_type(16)));
typedef int intx8 __attribute__((ext_vector_type(8)));

// pack 8 fp32 -> 8 fp8 e4m3 (OCP, RNE, saturating) as int2
__device__ __forceinline__ int2 pack_fp8x8(float4 a0, float4 a1) {
    int w0 = __builtin_amdgcn_cvt_pk_fp8_f32(a0.x, a0.y, 0, false);
    w0 = __builtin_amdgcn_cvt_pk_fp8_f32(a0.z, a0.w, w0, true);
    int w1 = __builtin_amdgcn_cvt_pk_fp8_f32(a1.x, a1.y, 0, false);
    w1 = __builtin_amdgcn_cvt_pk_fp8_f32(a1.z, a1.w, w1, true);
    return make_int2(w0, w1);
}

// ---------------------------------------------------------------------------
// Kernel 1: merged prep+gather. R7 CHANGE: anchor-block -> row mapping is
// XCD-MATCHED: block b (XCD b&7 under round-robin dispatch) handles row-block
// (b&7)*256 + (b>>3), so XCD x writes anchor rows [x*1024,(x+1)*1024) of
// A/ri/pos into its OWN L2. k_gemm reads them from the same XCD -> local-L2
// hit instead of a dirty-remote-line coherence round-trip (the hypothesized
// invisible wall that pinned 7 GEMM structures at ~40us).
// A and G remain K-BLOCK-MAJOR: A_t[kb][row][64], G_t[kb][g][64].
// ---------------------------------------------------------------------------
__global__ __launch_bounds__(256) void k_prep(
    const float* __restrict__ zi, const float* __restrict__ zj,
    const int* __restrict__ perm,
    float* __restrict__ ri_arr, float* __restrict__ pos_arr,
    unsigned char* __restrict__ A,
    float4* __restrict__ kmeta, unsigned char* __restrict__ G,
    float* __restrict__ rowacc, float* __restrict__ out)
{
    int w = threadIdx.x >> 6, l = threadIdx.x & 63;
    if (blockIdx.x < 2048) {
        if (blockIdx.x < 64)
            rowacc[blockIdx.x * 256 + threadIdx.x] = 0.f;   // pe[8192] ++ pc[8192]
        if (blockIdx.x == 0 && threadIdx.x < 3) out[threadIdx.x] = 0.f;
        // XCD-matched row block: XCD (b&7) owns anchor group (b&7)*1024..+1024
        int rb = (blockIdx.x & 7) * 256 + (blockIdx.x >> 3);
        int row = rb * 4 + w;
        const float4* zi4 = (const float4*)(zi + (size_t)row * D_SZ);
        const float4* zj4 = (const float4*)(zj + (size_t)row * D_SZ);
        float4 a0 = zi4[2 * l], a1 = zi4[2 * l + 1];
        float4 b0 = zj4[2 * l], b1 = zj4[2 * l + 1];
        float si = a0.x * a0.x + a0.y * a0.y + a0.z * a0.z + a0.w * a0.w
                 + a1.x * a1.x + a1.y * a1.y + a1.z * a1.z + a1.w * a1.w;
        float sj = b0.x * b0.x + b0.y * b0.y + b0.z * b0.z + b0.w * b0.w
                 + b1.x * b1.x + b1.y * b1.y + b1.z * b1.z + b1.w * b1.w;
        float dd = a0.x * b0.x + a0.y * b0.y + a0.z * b0.z + a0.w * b0.w
                 + a1.x * b1.x + a1.y * b1.y + a1.z * b1.z + a1.w * b1.w;
        for (int m = 1; m < 64; m <<= 1) {
            si += __shfl_xor(si, m);
            sj += __shfl_xor(sj, m);
            dd += __shfl_xor(dd, m);
        }
        if (l == 0) {
            float ni = sqrtf(si), nj = sqrtf(sj);
            ri_arr[row] = INV_T / fmaxf(ni, 1e-6f);   // norms ~22; eps never binds
            pos_arr[row] = dd / fmaxf(ni * nj, EPSV) * INV_T;
        }
        // kb-major store: A_t[l>>3][row][ (l&7)*8 .. +8 )
        *(int2*)(A + ((size_t)(l >> 3) * B_SZ + row) * 64 + (l & 7) * 8)
            = pack_fp8x8(a0, a1);
    } else {
        __shared__ float srj[4];
        int g = (blockIdx.x - 2048) * 4 + w;        // 0..4095
        int c0 = perm[g >> 1];
        int c = c0 + (g & 1);                       // actual z_j row
        const float4* src = (const float4*)(zj + (size_t)c * D_SZ);
        float4 a0 = src[2 * l], a1 = src[2 * l + 1];
        float s = a0.x * a0.x + a0.y * a0.y + a0.z * a0.z + a0.w * a0.w
                + a1.x * a1.x + a1.y * a1.y + a1.z * a1.z + a1.w * a1.w;
        for (int m = 1; m < 64; m <<= 1) s += __shfl_xor(s, m);
        if (l == 0) srj[w] = 1.0f / fmaxf(sqrtf(s), 1e-6f);
        __syncthreads();
        if ((w & 1) == 0 && l == 0)
            kmeta[g >> 1] = make_float4(srj[w], srj[w + 1],
                                        __int_as_float(c0), 0.f);
        *(int2*)(G + ((size_t)(l >> 3) * G_SZ + g) * 64 + (l & 7) * 8)
            = pack_fp8x8(a0, a1);
    }
}

// ---------------------------------------------------------------------------
// Kernel 2 (R17): R5's verified reg-staged GEMM core, byte-identical except
// the tile->block map. XCD-AFFINITY: xcd = bid&7; aTile = xcd*8 + (s&7) so
// every block's A panel / ri / pos / rowacc atomics are LOCAL to the XCD
// that wrote them (prep's matching remap). Only G (2 MB) is read cross-XCD,
// once, then L2-resident per XCD (2 MB < 4 MB). Cross-XCD dirty-line
// traffic: ~190 MB -> ~16 MB.
// S^T = G . A^T, tile 256(g) x 128(anchor), 1024 blocks x 512 thr (8 waves).
// ---------------------------------------------------------------------------
__global__ __launch_bounds__(512, 2) void k_gemm(
    const unsigned char* __restrict__ A,    // [8][8192][64] fp8  kb-major
    const unsigned char* __restrict__ G,    // [8][4096][64] fp8  kb-major
    const float4* __restrict__ kmeta,       // [2048]  {rj0, rj1, c0f, -}
    const float* __restrict__ ri_arr,       // [8192]  INV_T/ni
    const float* __restrict__ pos_arr,      // [8192]
    float* __restrict__ rowacc)             // [2][8192] atomic accumulators
{
    __shared__ unsigned char Asl[2][128 * 64];   // anchor tiles, 8 KB each
    __shared__ unsigned char Gsl[2][256 * 64];   // g tiles, 16 KB each
    __shared__ float4 kms[128];                  // this gTile's kmeta slice
    const int tid = threadIdx.x;
    const int l = tid & 63, w = tid >> 6;
    const int wm = w >> 2, wn = w & 3;      // wm: g-half (0..1), wn: anchor quarter
    const int ln = l & 31, q = l >> 5;      // 32x32 MFMA lane decomposition

    // XCD-affinity map: 1024 blocks; anchors local, G shared read-only
    const int bid = blockIdx.x;
    const int xcd = bid & 7;
    const int sl = bid >> 3;                // 0..127
    const int aTile = xcd * 8 + (sl & 7);   // 0..63: anchor panel IN THIS XCD's group
    const int gTile = sl >> 3;              // 0..15: G panel (all XCDs read all)
    const int gBase = gTile * 256;
    const int aBase = aTile * 128;

    // LDS dest for a linear 16B chunk fc: row r = fc>>2, col s = fc&3 stored
    // at col s ^ ((r^(r>>2))&3). Same LDS content as R4's source-permute.
    auto lds_slot = [](int fc) {
        int r = fc >> 2, c = fc & 3;
        int sc = c ^ ((r ^ (r >> 2)) & 3);
        return r * 64 + sc * 16;
    };
    const int aDst  = lds_slot(tid);         // A: 512 chunks, one per thread
    const int gDst0 = lds_slot(tid);         // G: 1024 chunks, two per thread
    const int gDst1 = lds_slot(tid + 512);

    floatx16 acc[4] = {};                   // [tm: g-subtile]; anchor frag = 1

    // frag read addresses (bytes): lane needs pre-swizzle chunks {2q, 2q+1}
    int aAddr[2], gAddr[4][2];
    {
        int ar = wn * 32 + ln;              // anchor row in tile (N-operand)
        int xa = (ar ^ (ar >> 2)) & 3;
        aAddr[0] = ar * 64 + ((2 * q) ^ xa) * 16;
        aAddr[1] = ar * 64 + ((2 * q + 1) ^ xa) * 16;
    }
    #pragma unroll
    for (int tm = 0; tm < 4; ++tm) {
        int gr = wm * 128 + tm * 32 + ln;   // g row in tile (M-operand)
        int xg = (gr ^ (gr >> 2)) & 3;
        gAddr[tm][0] = gr * 64 + ((2 * q) ^ xg) * 16;
        gAddr[tm][1] = gr * 64 + ((2 * q + 1) ^ xg) * 16;
    }

    // ---- prologue: epilogue data + kms, plus first staging group ----
    const int anc = aBase + wn * 32 + ln;
    const float riv = ri_arr[anc];          // INV_T / ni  (XCD-local line)
    const float pv = pos_arr[anc];
    if (tid < 128) kms[tid] = kmeta[gTile * 128 + tid];

    // staging registers, ping-pong across unrolled iterations (static idx)
    int4 ra[2], rg0[2], rg1[2];
    ra[0]  = *(const int4*)(A + ((size_t)0 * B_SZ + aBase) * 64 + tid * 16);
    rg0[0] = *(const int4*)(G + ((size_t)0 * G_SZ + gBase) * 64 + tid * 16);
    rg1[0] = *(const int4*)(G + ((size_t)0 * G_SZ + gBase) * 64 + (tid + 512) * 16);

    #pragma unroll
    for (int kb = 0; kb < 8; ++kb) {
        const int cur = kb & 1;
        // write staged group kb into buf[cur]; compiler inserts the counted
        // vmcnt wait for exactly these three loads.
        *(int4*)&Asl[cur][aDst]  = ra[cur];
        *(int4*)&Gsl[cur][gDst0] = rg0[cur];
        *(int4*)&Gsl[cur][gDst1] = rg1[cur];
        // issue group kb+1 (vector loads; fully pipelined, fly across barrier)
        if (kb < 7) {
            const int nxt = cur ^ 1;
            ra[nxt]  = *(const int4*)(A + ((size_t)(kb + 1) * B_SZ + aBase) * 64 + tid * 16);
            rg0[nxt] = *(const int4*)(G + ((size_t)(kb + 1) * G_SZ + gBase) * 64 + tid * 16);
            rg1[nxt] = *(const int4*)(G + ((size_t)(kb + 1) * G_SZ + gBase) * 64 + (tid + 512) * 16);
        }
        // ds_writes must be LDS-visible before the barrier
        asm volatile("s_waitcnt lgkmcnt(0)" ::: "memory");
        __builtin_amdgcn_sched_barrier(0);
        __builtin_amdgcn_s_barrier();       // buf[cur] full for all waves

        intx8 af, gf[4];
        {
            int4 lo = *(const int4*)&Asl[cur][aAddr[0]];
            int4 hi = *(const int4*)&Asl[cur][aAddr[1]];
            af[0] = lo.x; af[1] = lo.y; af[2] = lo.z; af[3] = lo.w;
            af[4] = hi.x; af[5] = hi.y; af[6] = hi.z; af[7] = hi.w;
        }
        #pragma unroll
        for (int tm = 0; tm < 4; ++tm) {
            int4 lo = *(const int4*)&Gsl[cur][gAddr[tm][0]];
            int4 hi = *(const int4*)&Gsl[cur][gAddr[tm][1]];
            gf[tm][0] = lo.x; gf[tm][1] = lo.y; gf[tm][2] = lo.z; gf[tm][3] = lo.w;
            gf[tm][4] = hi.x; gf[tm][5] = hi.y; gf[tm][6] = hi.z; gf[tm][7] = hi.w;
        }
        // reads retire here -> next-next write to this slot (after B_{kb+1})
        // can never race them; also rule #18 fence before the MFMA cluster.
        asm volatile("s_waitcnt lgkmcnt(0)" ::: "memory");
        __builtin_amdgcn_sched_barrier(0);

        __builtin_amdgcn_s_setprio(1);      // T5
        #pragma unroll
        for (int tm = 0; tm < 4; ++tm)
            acc[tm] = __builtin_amdgcn_mfma_scale_f32_32x32x64_f8f6f4(
                gf[tm], af, acc[tm],
                0, 0,                       // cbsz/blgp = fp8 e4m3
                0, 0x7f7f7f7f,              // scale A: all-ones (2^0)
                0, 0x7f7f7f7f);             // scale B: all-ones (2^0)
        __builtin_amdgcn_s_setprio(0);
    }

    // ---- fused epilogue: pair-select then exp, in-register reduction ----
    // C/D layout (32x32): col = anchor = ln, local g = (re&3) + 8*(re>>2)
    // + 4*q (+tm*32 +wm*128). Regs 4j..4j+3 hold 4 consecutive g, i.e. local
    // column pairs kidx = wm*64 + tm*16 + 4j + 2q and kidx+1.
    float pe = 0.f, pc = 0.f;
    #pragma unroll
    for (int tm = 0; tm < 4; ++tm) {
        #pragma unroll
        for (int j = 0; j < 4; ++j) {
            int kidx = wm * 64 + tm * 16 + 4 * j + 2 * q;   // local k in [0,128)
            float4 m0 = kms[kidx];
            float4 m1 = kms[kidx + 1];
            #pragma unroll
            for (int p = 0; p < 2; ++p) {
                float4 md = p ? m1 : m0;
                int c0 = __float_as_int(md.z);
                int re = 4 * j + 2 * p;     // even-g reg; odd is re+1
                bool sel = (c0 >= anc);                 // use column c0+1
                float v = sel ? acc[tm][re + 1] : acc[tm][re];
                float rj = sel ? md.y : md.x;
                float logit = v * riv * rj;
                pe += __expf(logit);
                pc += (logit > pv) ? 1.f : 0.f;
            }
        }
    }
    pe += __shfl_xor(pe, 32);
    pc += __shfl_xor(pc, 32);
    if (q == 0) {
        atomicAdd(&rowacc[anc], pe);        // all writers of anc are same-XCD now
        atomicAdd(&rowacc[B_SZ + anc], pc);
    }
}

// ---------------------------------------------------------------------------
// Kernel 3: tiny finalize — one thread per row, then block+global reduce.
// ---------------------------------------------------------------------------
__global__ __launch_bounds__(256) void k_final(
    const float* __restrict__ rowacc, const float* __restrict__ pos_arr,
    float* __restrict__ out)
{
    int row = blockIdx.x * 256 + threadIdx.x;
    float pe = rowacc[row];
    float pc = rowacc[B_SZ + row];
    float pos = pos_arr[row];
    float loss = logf(__expf(pos) + pe) - pos;   // logsumexp - pos (logits bounded)
    float a1 = (pc < 0.5f) ? 1.f : 0.f;          // no neg strictly > pos
    float a5 = (pc < 4.5f) ? 1.f : 0.f;          // at most 4 negs strictly > pos
    for (int m = 1; m < 64; m <<= 1) {
        loss += __shfl_xor(loss, m);
        a1 += __shfl_xor(a1, m);
        a5 += __shfl_xor(a5, m);
    }
    __shared__ float red[3][4];
    int w = threadIdx.x >> 6, l = threadIdx.x & 63;
    if (l == 0) { red[0][w] = loss; red[1][w] = a1; red[2][w] = a5; }
    __syncthreads();
    if (threadIdx.x == 0) {
        float L = red[0][0] + red[0][1] + red[0][2] + red[0][3];
        float A1 = red[1][0] + red[1][1] + red[1][2] + red[1][3];
        float A5 = red[2][0] + red[2][1] + red[2][2] + red[2][3];
        atomicAdd(&out[0], L / (float)B_SZ);
        atomicAdd(&out[1], A1 * (100.f / (float)B_SZ));
        atomicAdd(&out[2], A5 * (100.f / (float)B_SZ));
    }
}

// ---------------------------------------------------------------------------
extern "C" void kernel_launch(void* const* d_in, const int* in_sizes, int n_in,
                              void* d_out, int out_size, void* d_ws, size_t ws_size,
                              hipStream_t stream)
{
    const float* zi = (const float*)d_in[0];
    const float* zj = (const float*)d_in[1];
    const int* perm = (const int*)d_in[2];
    float* out = (float*)d_out;

    // workspace layout (all 16B aligned)
    char* p = (char*)d_ws;
    unsigned char* A = (unsigned char*)p;    p += (size_t)B_SZ * D_SZ;          // 4 MB, kb-major
    unsigned char* G = (unsigned char*)p;    p += (size_t)2 * K_SZ * D_SZ;      // 2 MB, kb-major
    float* ri_arr = (float*)p;               p += (size_t)B_SZ * 4;
    float* pos_arr = (float*)p;              p += (size_t)B_SZ * 4;
    float4* kmeta = (float4*)p;              p += (size_t)K_SZ * 16;            // 32 KB
    float* rowacc = (float*)p;               p += (size_t)2 * B_SZ * 4;         // 64 KB

    k_prep<<<2048 + 1024, 256, 0, stream>>>(zi, zj, perm, ri_arr, pos_arr, A,
                                            kmeta, G, rowacc, out);
    k_gemm<<<1024, 512, 0, stream>>>(A, G, kmeta, ri_arr, pos_arr, rowacc);
    k_final<<<32, 256, 0, stream>>>(rowacc, pos_arr, out);
}